// Round 20
// baseline (77.602 us; speedup 1.0000x reference)
//
#include <hip/hip_runtime.h>
#include <cmath>
#include <cfloat>
#include <climits>

// FMA contraction enabled (default). Internal consistency is exact: all
// consumers compare values selected from the same computed/stored values.

static constexpr int BS = 16;
static constexpr int Qn = 4000;
static constexpr int Cn = 80;
static constexpr int Gn = 128;
static constexpr float kEPS = 1e-8f;

// Replay-invariance rules (rounds 5/16):
//  - every byte of d_out/d_ws holds exactly ONE value per call, identical
//    across calls (claims is zeroed by kP then accumulated by kF via
//    commutative atomics -> final value call-invariant; kM3 is the SOLE
//    writer of out plane 1, each byte written exactly once per call).
//
// d_ws: [0,8K) thrv | [8K,16K) thri | [16K,16K+F) F | [16K+F, +256K) claims

static constexpr size_t kThrvOff  = 0;
static constexpr size_t kThriOff  = 8 * 1024;
static constexpr size_t kFOff     = 16 * 1024;
static constexpr size_t kFBytes   = (size_t)BS * Cn * Qn * sizeof(float);
static constexpr size_t kClaimOff = kFOff + kFBytes;
static constexpr size_t kClaimBytes = (size_t)BS * Qn * sizeof(unsigned);

__device__ __forceinline__ float focal_cost(float l) {
    const float p = 1.0f / (1.0f + expf(-l));
    const float neg = (0.75f * (p * p)) * (-log1pf(-p + kEPS));
    const float pos = (0.25f * ((1.0f - p) * (1.0f - p))) * (-logf(p + kEPS));
    return pos - neg;
}

// ---------------------------------------------------------------------------
// kP: focal class cost, transposed into d_ws: F[b][c][q]. Also zeroes the
// claims array (32 entries per block) when provided.
// ---------------------------------------------------------------------------
__global__ __launch_bounds__(256) void kP_focal(
    const float* __restrict__ logits,   // [BS][Qn][Cn]
    float* __restrict__ F,              // [BS][Cn][Qn]
    unsigned* __restrict__ claims)      // [BS][Qn] or nullptr
{
    const int b  = blockIdx.y;
    const int q0 = blockIdx.x * 32;
    const int t  = threadIdx.x;

    if (claims != nullptr && t < 32)
        claims[(size_t)b * Qn + q0 + t] = 0u;

    __shared__ float s_f[32 * 81];      // [ql][c] padded

    const float* src = logits + ((size_t)b * Qn + q0) * Cn;
#pragma unroll
    for (int i = 0; i < 10; ++i) {
        const int idx = t + i * 256;    // < 2560 = 32*80
        const int ql = idx / 80, c = idx % 80;
        s_f[ql * 81 + c] = focal_cost(src[idx]);
    }
    __syncthreads();

    float* dst = F + (size_t)b * Cn * Qn;
#pragma unroll
    for (int i = 0; i < 10; ++i) {
        const int j = t + i * 256;
        const int c = j >> 5, ql = j & 31;
        dst[(size_t)c * Qn + q0 + ql] = s_f[ql * 81 + c];
    }
}

// ---------------------------------------------------------------------------
// kF v12 (proven rounds 18/19): unified stream + specialized selection.
// Thread 0 scatters the first k matched q's into claims via
// atomicAdd(1 | g<<8) when claims != nullptr (cnt in low byte <= 128,
// g-sum above; commutative -> deterministic).
// ---------------------------------------------------------------------------
__device__ __forceinline__ unsigned long long pack_ci(float c, int q) {
    const unsigned int u = __float_as_uint(c + 0.0f);       // -0.0 -> +0.0
    const unsigned int s = (u & 0x80000000u) ? ~u : (u | 0x80000000u);
    return ((unsigned long long)s << 32) | (unsigned int)q;
}

__device__ __forceinline__ unsigned long long shfl_xor_u64(unsigned long long v, int m) {
    const int lo = __shfl_xor((int)(unsigned int)v, m, 64);
    const int hi = __shfl_xor((int)(unsigned int)(v >> 32), m, 64);
    return ((unsigned long long)(unsigned int)hi << 32) | (unsigned int)lo;
}

__device__ __forceinline__ unsigned long long bitonic64_asc_u64(unsigned long long v, int lane) {
#pragma unroll
    for (int k = 2; k <= 64; k <<= 1) {
#pragma unroll
        for (int j = 32; j >= 1; j >>= 1) {
            if (j < k) {
                const unsigned long long o = shfl_xor_u64(v, j);
                const bool up = ((lane & k) == 0);
                const bool keepmin = (((lane & j) == 0) == up);
                const bool omin = (o < v);
                v = (keepmin == omin) ? o : v;
            }
        }
    }
    return v;
}

__device__ __forceinline__ float bitonic64_asc_f32(float v, int lane) {
#pragma unroll
    for (int k = 2; k <= 64; k <<= 1) {
#pragma unroll
        for (int j = 32; j >= 1; j >>= 1) {
            if (j < k) {
                const float o = __shfl_xor(v, j, 64);
                const bool up = ((lane & k) == 0);
                const bool keepmin = (((lane & j) == 0) == up);
                const bool omin = (o < v);
                v = (keepmin == omin) ? o : v;
            }
        }
    }
    return v;
}

__device__ __forceinline__ void ins10_vi(float (&cv)[10], int (&ci)[10],
                                         float v, int q) {
    bool le[10];
#pragma unroll
    for (int j = 0; j < 10; ++j) le[j] = (cv[j] <= v);   // FIFO among equals
#pragma unroll
    for (int j = 9; j >= 1; --j) {
        const float nv = le[j] ? cv[j] : (le[j - 1] ? v : cv[j - 1]);
        const int   ni = le[j] ? ci[j] : (le[j - 1] ? q : ci[j - 1]);
        cv[j] = nv; ci[j] = ni;
    }
    if (!le[0]) { cv[0] = v; ci[0] = q; }
}

__device__ __forceinline__ void ins10_desc(float (&iv)[10], float v) {
    bool ge[10];
#pragma unroll
    for (int j = 0; j < 10; ++j) ge[j] = (iv[j] >= v);
#pragma unroll
    for (int j = 9; j >= 1; --j)
        iv[j] = ge[j] ? iv[j] : (ge[j - 1] ? v : iv[j - 1]);
    if (!ge[0]) iv[0] = v;
}

template <bool USE_F>
__global__ __launch_bounds__(512, 8) void kF(
    const float* __restrict__ boxes,    // [BS][Qn][4]
    const int*   __restrict__ labels,   // [BS][Gn]
    const float* __restrict__ tboxes,   // [BS][Gn][4]
    const float* __restrict__ logits,   // [BS][Qn][Cn] (fallback gather)
    const float* __restrict__ F,        // [BS][Cn][Qn] in d_ws (primary)
    float* __restrict__ out,            // cost -> [b][0]
    float* __restrict__ thrv,           // [BS*Gn] threshold value
    int*   __restrict__ thri,           // [BS*Gn] threshold index
    unsigned* __restrict__ claims)      // [BS][Qn] or nullptr
{
    const int lane = threadIdx.x & 63;
    const int w8   = threadIdx.x >> 6;  // 0..7
    const int sub  = w8 & 3;
    const int r    = blockIdx.x;
    const int b    = r >> 7;
    const int g    = r & (Gn - 1);

    const float* tb = tboxes + (size_t)r * 4;
    const float tcx = tb[0], tcy = tb[1], tw = tb[2], th = tb[3];
    const float tx0 = tcx - 0.5f * tw, ty0 = tcy - 0.5f * th;
    const float tx1 = tcx + 0.5f * tw, ty1 = tcy + 0.5f * th;
    const float tarea = (tx1 - tx0) * (ty1 - ty0);

    const float4* brow = reinterpret_cast<const float4*>(boxes) + (size_t)b * Qn;
    const int lab = labels[r];
    const float* Frow = USE_F ? (F + ((size_t)b * Cn + lab) * Qn) : nullptr;
    const float* lcol = USE_F ? nullptr : (logits + (size_t)b * Qn * Cn + lab);
    float* crow = out + (size_t)(b * 2) * Gn * Qn + (size_t)g * Qn;

    __shared__ float              s_cost[4096];    // 16 KB, block-linear by q
    __shared__ float              s_iou[4096];     // 16 KB
    __shared__ unsigned long long s_ccb[4][64];    // cost candidates
    __shared__ float              s_icb[4][64];    // iou candidates
    __shared__ int                s_cnt[8];
    __shared__ unsigned long long s_ce[4][12];     // sorted cost keys
    __shared__ float              s_if[4][12];     // sorted iou values
    __shared__ float              s_T[8];

    if (lane == 0) s_cnt[w8] = 0;

    float trk = (w8 < 4) ? INFINITY : -INFINITY;   // cost-min or iou-max

    // ---------------- pass 1: unified stream ----------------
#pragma unroll
    for (int it = 0; it < 2; ++it) {
        const int q0 = w8 * 512 + it * 256 + (lane << 2);
        if ((it == 0) || (q0 < Qn)) {              // body 0 guard-free
            float cls4[4];
            if (USE_F) {
                const float4 f4 = *reinterpret_cast<const float4*>(Frow + q0);
                cls4[0] = f4.x; cls4[1] = f4.y; cls4[2] = f4.z; cls4[3] = f4.w;
            } else {
#pragma unroll
                for (int e = 0; e < 4; ++e)
                    cls4[e] = focal_cost(lcol[(size_t)(q0 + e) * Cn]);
            }
            float c4[4], io4[4];
#pragma unroll
            for (int e = 0; e < 4; ++e) {
                const float cls = cls4[e];
                const float4 bb = brow[q0 + e];
                const float cx = bb.x, cy = bb.y, w = bb.z, h = bb.w;
                const float x0 = cx - 0.5f * w, y0 = cy - 0.5f * h;
                const float x1 = cx + 0.5f * w, y1 = cy + 0.5f * h;
                const float area1 = (x1 - x0) * (y1 - y0);
                const float l1 = ((fabsf(cx - tcx) + fabsf(cy - tcy))
                                  + fabsf(w - tw)) + fabsf(h - th);
                const float ltx = fmaxf(x0, tx0), lty = fmaxf(y0, ty0);
                const float rbx = fminf(x1, tx1), rby = fminf(y1, ty1);
                const float iw = fmaxf(rbx - ltx, 0.0f), ih = fmaxf(rby - lty, 0.0f);
                const float inter = iw * ih;
                const float uni = (area1 + tarea) - inter;
                const float iou = inter / (uni + kEPS);
                const float cltx = fminf(x0, tx0), clty = fminf(y0, ty0);
                const float crbx = fmaxf(x1, tx1), crby = fmaxf(y1, ty1);
                const float cw = fmaxf(crbx - cltx, 0.0f), ch = fmaxf(crby - clty, 0.0f);
                const float areac = cw * ch;
                const float giou = iou - (areac - uni) / (areac + kEPS);

                const float cost = (5.0f * l1 + 2.0f * cls) + 2.0f * (-giou);
                c4[e] = cost; io4[e] = iou;
            }
            if (w8 < 4) {
                trk = fminf(trk, fminf(fminf(c4[0], c4[1]), fminf(c4[2], c4[3])));
            } else {
                trk = fmaxf(trk, fmaxf(fmaxf(io4[0], io4[1]), fmaxf(io4[2], io4[3])));
            }
            float4 cv4; cv4.x = c4[0]; cv4.y = c4[1]; cv4.z = c4[2]; cv4.w = c4[3];
            float4 iv4; iv4.x = io4[0]; iv4.y = io4[1]; iv4.z = io4[2]; iv4.w = io4[3];
            *reinterpret_cast<float4*>(crow + q0) = cv4;
            *reinterpret_cast<float4*>(&s_cost[q0]) = cv4;
            *reinterpret_cast<float4*>(&s_iou[q0]) = iv4;
        } else {
            float4 pi; pi.x = INFINITY; pi.y = INFINITY; pi.z = INFINITY; pi.w = INFINITY;
            float4 ni; ni.x = -INFINITY; ni.y = -INFINITY; ni.z = -INFINITY; ni.w = -INFINITY;
            *reinterpret_cast<float4*>(&s_cost[q0]) = pi;
            *reinterpret_cast<float4*>(&s_iou[q0]) = ni;
        }
    }

    // per-wave threshold: 10th extreme of the 64 lane extremes.
    const float sorted = bitonic64_asc_f32(trk, lane);
    const float Tw = __shfl(sorted, (w8 < 4) ? 9 : 54, 64);
    if (lane == 0) s_T[w8] = Tw;
    __syncthreads();                    // stashes + thresholds visible

    if (w8 < 4) {
        // ============ cost selection over quarter [sub*1024, +1024) ============
        const float T = fminf(fminf(s_T[0], s_T[1]), fminf(s_T[2], s_T[3]));
        const int base = sub * 1024;
#pragma unroll
        for (int it = 0; it < 4; ++it) {
            const int idx = base + it * 256 + (lane << 2);
            const float4 c4 = *reinterpret_cast<const float4*>(&s_cost[idx]);
#pragma unroll
            for (int e = 0; e < 4; ++e) {
                const float c = (e == 0) ? c4.x : (e == 1) ? c4.y
                              : (e == 2) ? c4.z : c4.w;
                if (c <= T) {                       // INF padding never passes
                    const int slot = atomicAdd(&s_cnt[w8], 1);
                    if (slot < 64) s_ccb[sub][slot] = pack_ci(c, idx + e);
                }
            }
        }

        const int cnt = s_cnt[w8];
        if (cnt <= 64) {
            unsigned long long v = (lane < cnt) ? s_ccb[sub][lane] : ~0ull;
            v = bitonic64_asc_u64(v, lane);
            if (lane < 12) s_ce[sub][lane] = (lane < 10) ? v : ~0ull;
        } else {
            // exact fallback over this wave's range
            float cv[10]; int ci[10];
#pragma unroll
            for (int j = 0; j < 10; ++j) { cv[j] = INFINITY; ci[j] = INT_MAX; }
#pragma unroll
            for (int it = 0; it < 4; ++it) {
                const int idx = base + it * 256 + (lane << 2);
                const float4 c4 = *reinterpret_cast<const float4*>(&s_cost[idx]);
                ins10_vi(cv, ci, c4.x, idx);
                ins10_vi(cv, ci, c4.y, idx + 1);
                ins10_vi(cv, ci, c4.z, idx + 2);
                ins10_vi(cv, ci, c4.w, idx + 3);
            }
#pragma unroll
            for (int t = 0; t < 10; ++t) {
                float m = cv[0];
#pragma unroll
                for (int d = 1; d <= 32; d <<= 1)
                    m = fminf(m, __shfl_xor(m, d, 64));
                int cq = (cv[0] == m) ? ci[0] : INT_MAX;
#pragma unroll
                for (int d = 1; d <= 32; d <<= 1)
                    cq = min(cq, __shfl_xor(cq, d, 64));
                if (lane == 0) s_ce[sub][t] = pack_ci(m, cq);
                const bool own = (cv[0] == m) && (ci[0] == cq);
                if (own) {
#pragma unroll
                    for (int j = 0; j < 9; ++j) { cv[j] = cv[j + 1]; ci[j] = ci[j + 1]; }
                    cv[9] = INFINITY; ci[9] = INT_MAX;
                }
            }
            if (lane < 2) s_ce[sub][10 + lane] = ~0ull;
        }
    } else {
        // ============ iou selection over quarter [sub*1024, +1024) ============
        const float T = fmaxf(fmaxf(s_T[4], s_T[5]), fmaxf(s_T[6], s_T[7]));
        const int base = sub * 1024;
#pragma unroll
        for (int it = 0; it < 4; ++it) {
            const int idx = base + it * 256 + (lane << 2);
            const float4 i4 = *reinterpret_cast<const float4*>(&s_iou[idx]);
#pragma unroll
            for (int e = 0; e < 4; ++e) {
                const float v = (e == 0) ? i4.x : (e == 1) ? i4.y
                              : (e == 2) ? i4.z : i4.w;
                if (v >= T) {                       // -INF padding never passes
                    const int slot = atomicAdd(&s_cnt[w8], 1);
                    if (slot < 64) s_icb[sub][slot] = v;
                }
            }
        }

        const int cnt = s_cnt[w8];
        if (cnt <= 64) {
            float v = (lane < cnt) ? s_icb[sub][lane] : -INFINITY;
            v = bitonic64_asc_f32(v, lane);          // lane 63 = max
            if (lane >= 54) s_if[sub][63 - lane] = v;  // top-10 descending
            if (lane < 2) s_if[sub][10 + lane] = -INFINITY;
        } else {
            // exact fallback over this wave's range
            float iv[10];
#pragma unroll
            for (int j = 0; j < 10; ++j) iv[j] = -INFINITY;
#pragma unroll
            for (int it = 0; it < 4; ++it) {
                const int idx = base + it * 256 + (lane << 2);
                const float4 i4 = *reinterpret_cast<const float4*>(&s_iou[idx]);
                ins10_desc(iv, i4.x);
                ins10_desc(iv, i4.y);
                ins10_desc(iv, i4.z);
                ins10_desc(iv, i4.w);
            }
#pragma unroll
            for (int t = 0; t < 10; ++t) {
                float m = iv[0];
#pragma unroll
                for (int d = 1; d <= 32; d <<= 1)
                    m = fmaxf(m, __shfl_xor(m, d, 64));
                if (lane == 0) s_if[sub][t] = m;
                const bool own0 = (iv[0] == m);
                const unsigned long long bal = __ballot(own0);
                if (own0 && lane == __ffsll((long long)bal) - 1) {
#pragma unroll
                    for (int j = 0; j < 9; ++j) iv[j] = iv[j + 1];
                    iv[9] = -INFINITY;
                }
            }
            if (lane < 2) s_if[sub][10 + lane] = -INFINITY;
        }
    }

    __syncthreads();

    if (threadIdx.x == 0) {
        // iou: 4-way descending merge; sum in descending order (same float
        // add sequence as reference top_k -> sum; equal values commute).
        int p0 = 0, p1 = 0, p2 = 0, p3 = 0;
        float s = 0.0f;
#pragma unroll
        for (int t = 0; t < 10; ++t) {
            const float a0 = s_if[0][p0], a1 = s_if[1][p1];
            const float a2 = s_if[2][p2], a3 = s_if[3][p3];
            const float mx = fmaxf(fmaxf(a0, a1), fmaxf(a2, a3));
            if (a0 == mx) ++p0;
            else if (a1 == mx) ++p1;
            else if (a2 == mx) ++p2;
            else ++p3;
            s += mx;
        }
        int k = (int)s;                 // trunc (s >= 0)
        if (k < 1) k = 1;
        if (k > 10) k = 10;

        // cost: 4-way ascending lex merge on packed u64 (keys unique);
        // capture t == k-1; scatter claims for t < k (the matched set).
        p0 = 0; p1 = 0; p2 = 0; p3 = 0;
        unsigned long long key = 0;
#pragma unroll
        for (int t = 0; t < 10; ++t) {
            const unsigned long long a0 = s_ce[0][p0], a1 = s_ce[1][p1];
            const unsigned long long a2 = s_ce[2][p2], a3 = s_ce[3][p3];
            unsigned long long mn = a0;
            if (a1 < mn) mn = a1;
            if (a2 < mn) mn = a2;
            if (a3 < mn) mn = a3;
            if (a0 == mn) ++p0;
            else if (a1 == mn) ++p1;
            else if (a2 == mn) ++p2;
            else ++p3;
            if (t == k - 1) key = mn;
            if (claims != nullptr && t < k) {
                const int q = (int)(unsigned int)mn;
                atomicAdd(&claims[(size_t)b * Qn + q], 1u | ((unsigned)g << 8));
            }
        }
        const unsigned int su = (unsigned int)(key >> 32);
        thrv[r] = __uint_as_float((su & 0x80000000u) ? (su ^ 0x80000000u) : ~su);
        thri[r] = (int)(unsigned int)key;
    }
}

// ---------------------------------------------------------------------------
// kM3: sparse materialization with kC5's write geometry. Each thread owns a
// q-QUAD (4 columns, one uint4 claims read, 16 float4 stores); 8 waves
// g-split (16 g each). cnt==0 -> zeros; cnt==1 -> claimant g (payload);
// cnt>1 (rare) -> full-column first strict argmin (jnp.argmin semantics)
// via float4 column scan. Sole writer of out[b][1]; every cell written
// exactly once per call.
// ---------------------------------------------------------------------------
__global__ __launch_bounds__(512) void kM3(
    const float* __restrict__ outc,     // cost at [b][0][g][q]
    const unsigned* __restrict__ claims,
    float* __restrict__ out)            // matching at [b][1][g][q]
{
    const int b    = blockIdx.y;
    const int lane = threadIdx.x & 63;
    const int gh   = threadIdx.x >> 6;  // 0..7
    const int quad = blockIdx.x * 64 + lane;
    if (quad >= Qn / 4) return;         // no __syncthreads below
    const int q0 = quad * 4;

    const uint4 cv = *reinterpret_cast<const uint4*>(claims + (size_t)b * Qn + q0);
    int tg0 = -1, tg1 = -1, tg2 = -1, tg3 = -1;
    const unsigned c0 = cv.x & 0xFFu, c1 = cv.y & 0xFFu;
    const unsigned c2 = cv.z & 0xFFu, c3 = cv.w & 0xFFu;
    if (c0 == 1u) tg0 = (int)(cv.x >> 8);
    if (c1 == 1u) tg1 = (int)(cv.y >> 8);
    if (c2 == 1u) tg2 = (int)(cv.z >> 8);
    if (c3 == 1u) tg3 = (int)(cv.w >> 8);

    if ((c0 > 1u) | (c1 > 1u) | (c2 > 1u) | (c3 > 1u)) {
        // contested quad (~19%): scan the 4 columns (float4 per g row)
        const float* crow = outc + (size_t)(b * 2) * Gn * Qn + q0;
        float m0 = INFINITY, m1 = INFINITY, m2 = INFINITY, m3 = INFINITY;
        int a0 = 0, a1 = 0, a2 = 0, a3 = 0;
        for (int gg = 0; gg < Gn; ++gg) {
            const float4 c = *reinterpret_cast<const float4*>(crow + (size_t)gg * Qn);
            if (c.x < m0) { m0 = c.x; a0 = gg; }   // strict: first argmin
            if (c.y < m1) { m1 = c.y; a1 = gg; }
            if (c.z < m2) { m2 = c.z; a2 = gg; }
            if (c.w < m3) { m3 = c.w; a3 = gg; }
        }
        if (c0 > 1u) tg0 = a0;
        if (c1 > 1u) tg1 = a1;
        if (c2 > 1u) tg2 = a2;
        if (c3 > 1u) tg3 = a3;
    }

    float* mrow = out + (size_t)(b * 2 + 1) * Gn * Qn + q0;
    const int gbase = gh * 16;
#pragma unroll
    for (int j = 0; j < 16; ++j) {
        const int g = gbase + j;
        float4 o;
        o.x = (g == tg0) ? 1.0f : 0.0f;
        o.y = (g == tg1) ? 1.0f : 0.0f;
        o.z = (g == tg2) ? 1.0f : 0.0f;
        o.w = (g == tg3) ? 1.0f : 0.0f;
        *reinterpret_cast<float4*>(mrow + (size_t)g * Qn) = o;
    }
}

// ---------------------------------------------------------------------------
// kC v5 (fallback path only, proven round 15): dense matching + fixup.
// ---------------------------------------------------------------------------
__global__ __launch_bounds__(512) void kC5(
    const float* __restrict__ outc,     // cost at [b][0][g][q]
    const float* __restrict__ thrv,
    const int*   __restrict__ thri,
    float* __restrict__ out)            // matching at [b][1][g][q]
{
    const int b    = blockIdx.y;
    const int lane = threadIdx.x & 63;
    const int gh   = threadIdx.x >> 6;  // 0..7
    const int quad = blockIdx.x * 64 + lane;   // q-quad id, valid < Qn/4
    const int q0   = quad * 4;

    __shared__ float              s_tv[Gn];
    __shared__ int                s_ti[Gn];
    __shared__ unsigned long long s_mask[8][64];
    __shared__ float              s_mv0[8][64], s_mv1[8][64];
    __shared__ float              s_mv2[8][64], s_mv3[8][64];
    __shared__ unsigned           s_mg[8][64];

    if (threadIdx.x < Gn) {
        s_tv[threadIdx.x] = thrv[b * Gn + threadIdx.x];
        s_ti[threadIdx.x] = thri[b * Gn + threadIdx.x];
    }
    __syncthreads();

    const bool act = (quad < Qn / 4);
    const int gbase = gh * 16;
    unsigned long long mask = 0;
    float mv0 = INFINITY, mv1 = INFINITY, mv2 = INFINITY, mv3 = INFINITY;
    int mg0 = 0, mg1 = 0, mg2 = 0, mg3 = 0;

    if (act) {
        const float* crow = outc + (size_t)(b * 2) * Gn * Qn + q0;
#pragma unroll
        for (int j = 0; j < 16; ++j) {
            const int g = gbase + j;
            const float4 c = *reinterpret_cast<const float4*>(crow + (size_t)g * Qn);
            const float tvg = s_tv[g];
            const int   tig = s_ti[g];
            const bool t0 = (c.x < tvg) || (c.x == tvg && q0     <= tig);
            const bool t1 = (c.y < tvg) || (c.y == tvg && q0 + 1 <= tig);
            const bool t2 = (c.z < tvg) || (c.z == tvg && q0 + 2 <= tig);
            const bool t3 = (c.w < tvg) || (c.w == tvg && q0 + 3 <= tig);
            mask |= ((unsigned long long)t0 << j)
                  | ((unsigned long long)t1 << (16 + j))
                  | ((unsigned long long)t2 << (32 + j))
                  | ((unsigned long long)t3 << (48 + j));
            if (c.x < mv0) { mv0 = c.x; mg0 = g; }   // strict: first argmin
            if (c.y < mv1) { mv1 = c.y; mg1 = g; }
            if (c.z < mv2) { mv2 = c.z; mg2 = g; }
            if (c.w < mv3) { mv3 = c.w; mg3 = g; }
        }
    }
    s_mask[gh][lane] = mask;
    s_mv0[gh][lane] = mv0; s_mv1[gh][lane] = mv1;
    s_mv2[gh][lane] = mv2; s_mv3[gh][lane] = mv3;
    s_mg[gh][lane] = (unsigned)mg0 | ((unsigned)mg1 << 8)
                   | ((unsigned)mg2 << 16) | ((unsigned)mg3 << 24);
    __syncthreads();

    int n0 = 0, n1 = 0, n2 = 0, n3 = 0;
#pragma unroll
    for (int h = 0; h < 8; ++h) {
        const unsigned long long m = s_mask[h][lane];
        n0 += __popcll(m & 0xFFFFull);
        n1 += __popcll((m >> 16) & 0xFFFFull);
        n2 += __popcll((m >> 32) & 0xFFFFull);
        n3 += __popcll((m >> 48) & 0xFFFFull);
    }
    float b0 = s_mv0[0][lane], b1 = s_mv1[0][lane];
    float b2 = s_mv2[0][lane], b3 = s_mv3[0][lane];
    unsigned pk = s_mg[0][lane];
    int g0b = pk & 0xFF, g1b = (pk >> 8) & 0xFF;
    int g2b = (pk >> 16) & 0xFF, g3b = (pk >> 24) & 0xFF;
#pragma unroll
    for (int h = 1; h < 8; ++h) {                     // ascending h: first argmin
        const unsigned pkh = s_mg[h][lane];
        const float v0 = s_mv0[h][lane];
        if (v0 < b0) { b0 = v0; g0b = pkh & 0xFF; }
        const float v1 = s_mv1[h][lane];
        if (v1 < b1) { b1 = v1; g1b = (pkh >> 8) & 0xFF; }
        const float v2 = s_mv2[h][lane];
        if (v2 < b2) { b2 = v2; g2b = (pkh >> 16) & 0xFF; }
        const float v3 = s_mv3[h][lane];
        if (v3 < b3) { b3 = v3; g3b = (pkh >> 24) & 0xFF; }
    }
    const bool f0 = (n0 > 1), f1 = (n1 > 1), f2 = (n2 > 1), f3 = (n3 > 1);

    if (act) {
        float* mrow = out + (size_t)(b * 2 + 1) * Gn * Qn + q0;
#pragma unroll
        for (int j = 0; j < 16; ++j) {
            const int g = gbase + j;
            float4 o;
            o.x = (f0 ? (g == g0b) : ((mask >> j) & 1ull))        ? 1.0f : 0.0f;
            o.y = (f1 ? (g == g1b) : ((mask >> (16 + j)) & 1ull)) ? 1.0f : 0.0f;
            o.z = (f2 ? (g == g2b) : ((mask >> (32 + j)) & 1ull)) ? 1.0f : 0.0f;
            o.w = (f3 ? (g == g3b) : ((mask >> (48 + j)) & 1ull)) ? 1.0f : 0.0f;
            *reinterpret_cast<float4*>(mrow + (size_t)g * Qn) = o;
        }
    }
}

// ---------------------------------------------------------------------------
extern "C" void kernel_launch(void* const* d_in, const int* in_sizes, int n_in,
                              void* d_out, int out_size, void* d_ws, size_t ws_size,
                              hipStream_t stream) {
    (void)in_sizes; (void)n_in; (void)out_size;
    const float* logits = (const float*)d_in[0];
    const float* boxes  = (const float*)d_in[1];
    const int*   labels = (const int*)d_in[2];
    const float* tboxes = (const float*)d_in[3];
    float* out = (float*)d_out;

    float*    thrv   = (float*)   ((char*)d_ws + kThrvOff);   // [BS*Gn]
    int*      thri   = (int*)     ((char*)d_ws + kThriOff);   // [BS*Gn]
    float*    F      = (float*)   ((char*)d_ws + kFOff);      // [BS][Cn][Qn]
    unsigned* claims = (unsigned*)((char*)d_ws + kClaimOff);  // [BS][Qn]

    const bool use_f  = (ws_size >= kFOff + kFBytes);
    const bool sparse = (ws_size >= kClaimOff + kClaimBytes);

    dim3 gF(BS * Gn);                     // one row per block, 8 waves
    if (use_f && sparse) {
        dim3 gP(Qn / 32, BS);             // 125 x 16 (also zeroes claims)
        kP_focal<<<gP, 256, 0, stream>>>(logits, F, claims);
        kF<true><<<gF, 512, 0, stream>>>(boxes, labels, tboxes, logits, F,
                                         out, thrv, thri, claims);
        dim3 gM((Qn / 4 + 63) / 64, BS);  // 16 x 16, q-quads
        kM3<<<gM, 512, 0, stream>>>(out, claims, out);
    } else if (use_f) {
        dim3 gP(Qn / 32, BS);
        kP_focal<<<gP, 256, 0, stream>>>(logits, F, nullptr);
        kF<true><<<gF, 512, 0, stream>>>(boxes, labels, tboxes, logits, F,
                                         out, thrv, thri, nullptr);
        dim3 gC((Qn / 4 + 63) / 64, BS);
        kC5<<<gC, 512, 0, stream>>>(out, thrv, thri, out);
    } else {
        kF<false><<<gF, 512, 0, stream>>>(boxes, labels, tboxes, logits, nullptr,
                                          out, thrv, thri, nullptr);
        dim3 gC((Qn / 4 + 63) / 64, BS);
        kC5<<<gC, 512, 0, stream>>>(out, thrv, thri, out);
    }
}

// Round 21
// 67.912 us; speedup vs baseline: 1.1427x; 1.1427x over previous
//
#include <hip/hip_runtime.h>
#include <cmath>
#include <cfloat>
#include <climits>

// FMA contraction enabled (default). Internal consistency is exact: kC and
// pass-2 compare values selected from the same computed/stored values.

static constexpr int BS = 16;
static constexpr int Qn = 4000;
static constexpr int Cn = 80;
static constexpr int Gn = 128;
static constexpr float kEPS = 1e-8f;

// Replay-invariance rule (round 5): every byte of d_out/d_ws holds exactly
// ONE value per call, identical across calls.
// d_ws: [0,8K) thrv f32 | [8K,16K) thri i32 | [16K,..) F[b][c][q]

static constexpr size_t kThrvOff = 0;
static constexpr size_t kThriOff = 8 * 1024;
static constexpr size_t kFOff    = 16 * 1024;
static constexpr size_t kFBytes  = (size_t)BS * Cn * Qn * sizeof(float);

__device__ __forceinline__ float focal_cost(float l) {
    const float p = 1.0f / (1.0f + expf(-l));
    const float neg = (0.75f * (p * p)) * (-log1pf(-p + kEPS));
    const float pos = (0.25f * ((1.0f - p) * (1.0f - p))) * (-logf(p + kEPS));
    return pos - neg;
}

// ---------------------------------------------------------------------------
// kP: focal class cost, transposed into d_ws: F[b][c][q].
// ---------------------------------------------------------------------------
__global__ __launch_bounds__(256) void kP_focal(
    const float* __restrict__ logits,   // [BS][Qn][Cn]
    float* __restrict__ F)              // [BS][Cn][Qn]
{
    const int b  = blockIdx.y;
    const int q0 = blockIdx.x * 32;
    const int t  = threadIdx.x;

    __shared__ float s_f[32 * 81];      // [ql][c] padded

    const float* src = logits + ((size_t)b * Qn + q0) * Cn;
#pragma unroll
    for (int i = 0; i < 10; ++i) {
        const int idx = t + i * 256;    // < 2560 = 32*80
        const int ql = idx / 80, c = idx % 80;
        s_f[ql * 81 + c] = focal_cost(src[idx]);
    }
    __syncthreads();

    float* dst = F + (size_t)b * Cn * Qn;
#pragma unroll
    for (int i = 0; i < 10; ++i) {
        const int j = t + i * 256;
        const int c = j >> 5, ql = j & 31;
        dst[(size_t)c * Qn + q0 + ql] = s_f[ql * 81 + c];
    }
}

// ---------------------------------------------------------------------------
// kF v12 (proven round 18): unified stream + specialized selection.
// Pass 1: ALL 8 waves stream disjoint 512-elem segments, computing cost AND
// iou ONCE per element; cost -> global + s_cost stash; iou -> s_iou stash;
// waves 0-3 track per-lane cost-min, waves 4-7 per-lane iou-max.
// Thresholds: per-wave bitonic-64 of lane extremes -> T_w (order-stat
// containment); T = min(T0..T3) (cost), T' = max(T4..T7) (iou).
// Pass 2 (specialized): waves 0-3 scan their 1024-q quarter of s_cost for
// c <= T; waves 4-7 scan s_iou for v >= T'; append -> bitonic-64 ->
// sorted-10 per wave; thread 0 4-way merges. Overflow -> ins10 fallback.
// ---------------------------------------------------------------------------
__device__ __forceinline__ unsigned long long pack_ci(float c, int q) {
    const unsigned int u = __float_as_uint(c + 0.0f);       // -0.0 -> +0.0
    const unsigned int s = (u & 0x80000000u) ? ~u : (u | 0x80000000u);
    return ((unsigned long long)s << 32) | (unsigned int)q;
}

__device__ __forceinline__ unsigned long long shfl_xor_u64(unsigned long long v, int m) {
    const int lo = __shfl_xor((int)(unsigned int)v, m, 64);
    const int hi = __shfl_xor((int)(unsigned int)(v >> 32), m, 64);
    return ((unsigned long long)(unsigned int)hi << 32) | (unsigned int)lo;
}

__device__ __forceinline__ unsigned long long bitonic64_asc_u64(unsigned long long v, int lane) {
#pragma unroll
    for (int k = 2; k <= 64; k <<= 1) {
#pragma unroll
        for (int j = 32; j >= 1; j >>= 1) {
            if (j < k) {
                const unsigned long long o = shfl_xor_u64(v, j);
                const bool up = ((lane & k) == 0);
                const bool keepmin = (((lane & j) == 0) == up);
                const bool omin = (o < v);
                v = (keepmin == omin) ? o : v;
            }
        }
    }
    return v;
}

__device__ __forceinline__ float bitonic64_asc_f32(float v, int lane) {
#pragma unroll
    for (int k = 2; k <= 64; k <<= 1) {
#pragma unroll
        for (int j = 32; j >= 1; j >>= 1) {
            if (j < k) {
                const float o = __shfl_xor(v, j, 64);
                const bool up = ((lane & k) == 0);
                const bool keepmin = (((lane & j) == 0) == up);
                const bool omin = (o < v);
                v = (keepmin == omin) ? o : v;
            }
        }
    }
    return v;
}

__device__ __forceinline__ void ins10_vi(float (&cv)[10], int (&ci)[10],
                                         float v, int q) {
    bool le[10];
#pragma unroll
    for (int j = 0; j < 10; ++j) le[j] = (cv[j] <= v);   // FIFO among equals
#pragma unroll
    for (int j = 9; j >= 1; --j) {
        const float nv = le[j] ? cv[j] : (le[j - 1] ? v : cv[j - 1]);
        const int   ni = le[j] ? ci[j] : (le[j - 1] ? q : ci[j - 1]);
        cv[j] = nv; ci[j] = ni;
    }
    if (!le[0]) { cv[0] = v; ci[0] = q; }
}

__device__ __forceinline__ void ins10_desc(float (&iv)[10], float v) {
    bool ge[10];
#pragma unroll
    for (int j = 0; j < 10; ++j) ge[j] = (iv[j] >= v);
#pragma unroll
    for (int j = 9; j >= 1; --j)
        iv[j] = ge[j] ? iv[j] : (ge[j - 1] ? v : iv[j - 1]);
    if (!ge[0]) iv[0] = v;
}

template <bool USE_F>
__global__ __launch_bounds__(512, 8) void kF(
    const float* __restrict__ boxes,    // [BS][Qn][4]
    const int*   __restrict__ labels,   // [BS][Gn]
    const float* __restrict__ tboxes,   // [BS][Gn][4]
    const float* __restrict__ logits,   // [BS][Qn][Cn] (fallback gather)
    const float* __restrict__ F,        // [BS][Cn][Qn] in d_ws (primary)
    float* __restrict__ out,            // cost -> [b][0]
    float* __restrict__ thrv,           // [BS*Gn] threshold value
    int*   __restrict__ thri)           // [BS*Gn] threshold index
{
    const int lane = threadIdx.x & 63;
    const int w8   = threadIdx.x >> 6;  // 0..7
    const int sub  = w8 & 3;
    const int r    = blockIdx.x;
    const int b    = r >> 7;
    const int g    = r & (Gn - 1);

    const float* tb = tboxes + (size_t)r * 4;
    const float tcx = tb[0], tcy = tb[1], tw = tb[2], th = tb[3];
    const float tx0 = tcx - 0.5f * tw, ty0 = tcy - 0.5f * th;
    const float tx1 = tcx + 0.5f * tw, ty1 = tcy + 0.5f * th;
    const float tarea = (tx1 - tx0) * (ty1 - ty0);

    const float4* brow = reinterpret_cast<const float4*>(boxes) + (size_t)b * Qn;
    const int lab = labels[r];
    const float* Frow = USE_F ? (F + ((size_t)b * Cn + lab) * Qn) : nullptr;
    const float* lcol = USE_F ? nullptr : (logits + (size_t)b * Qn * Cn + lab);
    float* crow = out + (size_t)(b * 2) * Gn * Qn + (size_t)g * Qn;

    __shared__ float              s_cost[4096];    // 16 KB, block-linear by q
    __shared__ float              s_iou[4096];     // 16 KB
    __shared__ unsigned long long s_ccb[4][64];    // cost candidates
    __shared__ float              s_icb[4][64];    // iou candidates
    __shared__ int                s_cnt[8];
    __shared__ unsigned long long s_ce[4][12];     // sorted cost keys
    __shared__ float              s_if[4][12];     // sorted iou values
    __shared__ float              s_T[8];

    if (lane == 0) s_cnt[w8] = 0;

    float trk = (w8 < 4) ? INFINITY : -INFINITY;   // cost-min or iou-max

    // ---------------- pass 1: unified stream ----------------
#pragma unroll
    for (int it = 0; it < 2; ++it) {
        const int q0 = w8 * 512 + it * 256 + (lane << 2);
        if ((it == 0) || (q0 < Qn)) {              // body 0 guard-free
            float cls4[4];
            if (USE_F) {
                const float4 f4 = *reinterpret_cast<const float4*>(Frow + q0);
                cls4[0] = f4.x; cls4[1] = f4.y; cls4[2] = f4.z; cls4[3] = f4.w;
            } else {
#pragma unroll
                for (int e = 0; e < 4; ++e)
                    cls4[e] = focal_cost(lcol[(size_t)(q0 + e) * Cn]);
            }
            float c4[4], io4[4];
#pragma unroll
            for (int e = 0; e < 4; ++e) {
                const float cls = cls4[e];
                const float4 bb = brow[q0 + e];
                const float cx = bb.x, cy = bb.y, w = bb.z, h = bb.w;
                const float x0 = cx - 0.5f * w, y0 = cy - 0.5f * h;
                const float x1 = cx + 0.5f * w, y1 = cy + 0.5f * h;
                const float area1 = (x1 - x0) * (y1 - y0);
                const float l1 = ((fabsf(cx - tcx) + fabsf(cy - tcy))
                                  + fabsf(w - tw)) + fabsf(h - th);
                const float ltx = fmaxf(x0, tx0), lty = fmaxf(y0, ty0);
                const float rbx = fminf(x1, tx1), rby = fminf(y1, ty1);
                const float iw = fmaxf(rbx - ltx, 0.0f), ih = fmaxf(rby - lty, 0.0f);
                const float inter = iw * ih;
                const float uni = (area1 + tarea) - inter;
                const float iou = inter / (uni + kEPS);
                const float cltx = fminf(x0, tx0), clty = fminf(y0, ty0);
                const float crbx = fmaxf(x1, tx1), crby = fmaxf(y1, ty1);
                const float cw = fmaxf(crbx - cltx, 0.0f), ch = fmaxf(crby - clty, 0.0f);
                const float areac = cw * ch;
                const float giou = iou - (areac - uni) / (areac + kEPS);

                const float cost = (5.0f * l1 + 2.0f * cls) + 2.0f * (-giou);
                c4[e] = cost; io4[e] = iou;
            }
            if (w8 < 4) {
                trk = fminf(trk, fminf(fminf(c4[0], c4[1]), fminf(c4[2], c4[3])));
            } else {
                trk = fmaxf(trk, fmaxf(fmaxf(io4[0], io4[1]), fmaxf(io4[2], io4[3])));
            }
            float4 cv4; cv4.x = c4[0]; cv4.y = c4[1]; cv4.z = c4[2]; cv4.w = c4[3];
            float4 iv4; iv4.x = io4[0]; iv4.y = io4[1]; iv4.z = io4[2]; iv4.w = io4[3];
            *reinterpret_cast<float4*>(crow + q0) = cv4;
            *reinterpret_cast<float4*>(&s_cost[q0]) = cv4;
            *reinterpret_cast<float4*>(&s_iou[q0]) = iv4;
        } else {
            float4 pi; pi.x = INFINITY; pi.y = INFINITY; pi.z = INFINITY; pi.w = INFINITY;
            float4 ni; ni.x = -INFINITY; ni.y = -INFINITY; ni.z = -INFINITY; ni.w = -INFINITY;
            *reinterpret_cast<float4*>(&s_cost[q0]) = pi;
            *reinterpret_cast<float4*>(&s_iou[q0]) = ni;
        }
    }

    // per-wave threshold: 10th extreme of the 64 lane extremes.
    const float sorted = bitonic64_asc_f32(trk, lane);
    const float Tw = __shfl(sorted, (w8 < 4) ? 9 : 54, 64);
    if (lane == 0) s_T[w8] = Tw;
    __syncthreads();                    // stashes + thresholds visible

    if (w8 < 4) {
        // ============ cost selection over quarter [sub*1024, +1024) ============
        const float T = fminf(fminf(s_T[0], s_T[1]), fminf(s_T[2], s_T[3]));
        const int base = sub * 1024;
#pragma unroll
        for (int it = 0; it < 4; ++it) {
            const int idx = base + it * 256 + (lane << 2);
            const float4 c4 = *reinterpret_cast<const float4*>(&s_cost[idx]);
#pragma unroll
            for (int e = 0; e < 4; ++e) {
                const float c = (e == 0) ? c4.x : (e == 1) ? c4.y
                              : (e == 2) ? c4.z : c4.w;
                if (c <= T) {                       // INF padding never passes
                    const int slot = atomicAdd(&s_cnt[w8], 1);
                    if (slot < 64) s_ccb[sub][slot] = pack_ci(c, idx + e);
                }
            }
        }

        const int cnt = s_cnt[w8];
        if (cnt <= 64) {
            unsigned long long v = (lane < cnt) ? s_ccb[sub][lane] : ~0ull;
            v = bitonic64_asc_u64(v, lane);
            if (lane < 12) s_ce[sub][lane] = (lane < 10) ? v : ~0ull;
        } else {
            // exact fallback over this wave's range
            float cv[10]; int ci[10];
#pragma unroll
            for (int j = 0; j < 10; ++j) { cv[j] = INFINITY; ci[j] = INT_MAX; }
#pragma unroll
            for (int it = 0; it < 4; ++it) {
                const int idx = base + it * 256 + (lane << 2);
                const float4 c4 = *reinterpret_cast<const float4*>(&s_cost[idx]);
                ins10_vi(cv, ci, c4.x, idx);
                ins10_vi(cv, ci, c4.y, idx + 1);
                ins10_vi(cv, ci, c4.z, idx + 2);
                ins10_vi(cv, ci, c4.w, idx + 3);
            }
#pragma unroll
            for (int t = 0; t < 10; ++t) {
                float m = cv[0];
#pragma unroll
                for (int d = 1; d <= 32; d <<= 1)
                    m = fminf(m, __shfl_xor(m, d, 64));
                int cq = (cv[0] == m) ? ci[0] : INT_MAX;
#pragma unroll
                for (int d = 1; d <= 32; d <<= 1)
                    cq = min(cq, __shfl_xor(cq, d, 64));
                if (lane == 0) s_ce[sub][t] = pack_ci(m, cq);
                const bool own = (cv[0] == m) && (ci[0] == cq);
                if (own) {
#pragma unroll
                    for (int j = 0; j < 9; ++j) { cv[j] = cv[j + 1]; ci[j] = ci[j + 1]; }
                    cv[9] = INFINITY; ci[9] = INT_MAX;
                }
            }
            if (lane < 2) s_ce[sub][10 + lane] = ~0ull;
        }
    } else {
        // ============ iou selection over quarter [sub*1024, +1024) ============
        const float T = fmaxf(fmaxf(s_T[4], s_T[5]), fmaxf(s_T[6], s_T[7]));
        const int base = sub * 1024;
#pragma unroll
        for (int it = 0; it < 4; ++it) {
            const int idx = base + it * 256 + (lane << 2);
            const float4 i4 = *reinterpret_cast<const float4*>(&s_iou[idx]);
#pragma unroll
            for (int e = 0; e < 4; ++e) {
                const float v = (e == 0) ? i4.x : (e == 1) ? i4.y
                              : (e == 2) ? i4.z : i4.w;
                if (v >= T) {                       // -INF padding never passes
                    const int slot = atomicAdd(&s_cnt[w8], 1);
                    if (slot < 64) s_icb[sub][slot] = v;
                }
            }
        }

        const int cnt = s_cnt[w8];
        if (cnt <= 64) {
            float v = (lane < cnt) ? s_icb[sub][lane] : -INFINITY;
            v = bitonic64_asc_f32(v, lane);          // lane 63 = max
            if (lane >= 54) s_if[sub][63 - lane] = v;  // top-10 descending
            if (lane < 2) s_if[sub][10 + lane] = -INFINITY;
        } else {
            // exact fallback over this wave's range
            float iv[10];
#pragma unroll
            for (int j = 0; j < 10; ++j) iv[j] = -INFINITY;
#pragma unroll
            for (int it = 0; it < 4; ++it) {
                const int idx = base + it * 256 + (lane << 2);
                const float4 i4 = *reinterpret_cast<const float4*>(&s_iou[idx]);
                ins10_desc(iv, i4.x);
                ins10_desc(iv, i4.y);
                ins10_desc(iv, i4.z);
                ins10_desc(iv, i4.w);
            }
#pragma unroll
            for (int t = 0; t < 10; ++t) {
                float m = iv[0];
#pragma unroll
                for (int d = 1; d <= 32; d <<= 1)
                    m = fmaxf(m, __shfl_xor(m, d, 64));
                if (lane == 0) s_if[sub][t] = m;
                const bool own0 = (iv[0] == m);
                const unsigned long long bal = __ballot(own0);
                if (own0 && lane == __ffsll((long long)bal) - 1) {
#pragma unroll
                    for (int j = 0; j < 9; ++j) iv[j] = iv[j + 1];
                    iv[9] = -INFINITY;
                }
            }
            if (lane < 2) s_if[sub][10 + lane] = -INFINITY;
        }
    }

    __syncthreads();

    if (threadIdx.x == 0) {
        // iou: 4-way descending merge; sum in descending order (same float
        // add sequence as reference top_k -> sum; equal values commute).
        int p0 = 0, p1 = 0, p2 = 0, p3 = 0;
        float s = 0.0f;
#pragma unroll
        for (int t = 0; t < 10; ++t) {
            const float a0 = s_if[0][p0], a1 = s_if[1][p1];
            const float a2 = s_if[2][p2], a3 = s_if[3][p3];
            const float mx = fmaxf(fmaxf(a0, a1), fmaxf(a2, a3));
            if (a0 == mx) ++p0;
            else if (a1 == mx) ++p1;
            else if (a2 == mx) ++p2;
            else ++p3;
            s += mx;
        }
        int k = (int)s;                 // trunc (s >= 0)
        if (k < 1) k = 1;
        if (k > 10) k = 10;

        // cost: 4-way ascending lex merge on packed u64 (keys unique);
        // capture t == k-1.
        p0 = 0; p1 = 0; p2 = 0; p3 = 0;
        unsigned long long key = 0;
#pragma unroll
        for (int t = 0; t < 10; ++t) {
            const unsigned long long a0 = s_ce[0][p0], a1 = s_ce[1][p1];
            const unsigned long long a2 = s_ce[2][p2], a3 = s_ce[3][p3];
            unsigned long long mn = a0;
            if (a1 < mn) mn = a1;
            if (a2 < mn) mn = a2;
            if (a3 < mn) mn = a3;
            if (a0 == mn) ++p0;
            else if (a1 == mn) ++p1;
            else if (a2 == mn) ++p2;
            else ++p3;
            if (t == k - 1) key = mn;
        }
        const unsigned int su = (unsigned int)(key >> 32);
        thrv[r] = __uint_as_float((su & 0x80000000u) ? (su ^ 0x80000000u) : ~su);
        thri[r] = (int)(unsigned int)key;
    }
}

// ---------------------------------------------------------------------------
// kC v5 (proven round 15): dense matching + (>1 matched) argmin fixup.
// Each thread owns a float4 q-quad; 8 waves g-split (16 g each).
// Sole writer of out[b][1].
// ---------------------------------------------------------------------------
__global__ __launch_bounds__(512) void kC5(
    const float* __restrict__ outc,     // cost at [b][0][g][q]
    const float* __restrict__ thrv,
    const int*   __restrict__ thri,
    float* __restrict__ out)            // matching at [b][1][g][q]
{
    const int b    = blockIdx.y;
    const int lane = threadIdx.x & 63;
    const int gh   = threadIdx.x >> 6;  // 0..7
    const int quad = blockIdx.x * 64 + lane;   // q-quad id, valid < Qn/4
    const int q0   = quad * 4;

    __shared__ float              s_tv[Gn];
    __shared__ int                s_ti[Gn];
    __shared__ unsigned long long s_mask[8][64];
    __shared__ float              s_mv0[8][64], s_mv1[8][64];
    __shared__ float              s_mv2[8][64], s_mv3[8][64];
    __shared__ unsigned           s_mg[8][64];

    if (threadIdx.x < Gn) {
        s_tv[threadIdx.x] = thrv[b * Gn + threadIdx.x];
        s_ti[threadIdx.x] = thri[b * Gn + threadIdx.x];
    }
    __syncthreads();

    const bool act = (quad < Qn / 4);
    const int gbase = gh * 16;
    unsigned long long mask = 0;
    float mv0 = INFINITY, mv1 = INFINITY, mv2 = INFINITY, mv3 = INFINITY;
    int mg0 = 0, mg1 = 0, mg2 = 0, mg3 = 0;

    if (act) {
        const float* crow = outc + (size_t)(b * 2) * Gn * Qn + q0;
#pragma unroll
        for (int j = 0; j < 16; ++j) {
            const int g = gbase + j;
            const float4 c = *reinterpret_cast<const float4*>(crow + (size_t)g * Qn);
            const float tvg = s_tv[g];
            const int   tig = s_ti[g];
            const bool t0 = (c.x < tvg) || (c.x == tvg && q0     <= tig);
            const bool t1 = (c.y < tvg) || (c.y == tvg && q0 + 1 <= tig);
            const bool t2 = (c.z < tvg) || (c.z == tvg && q0 + 2 <= tig);
            const bool t3 = (c.w < tvg) || (c.w == tvg && q0 + 3 <= tig);
            mask |= ((unsigned long long)t0 << j)
                  | ((unsigned long long)t1 << (16 + j))
                  | ((unsigned long long)t2 << (32 + j))
                  | ((unsigned long long)t3 << (48 + j));
            if (c.x < mv0) { mv0 = c.x; mg0 = g; }   // strict: first argmin
            if (c.y < mv1) { mv1 = c.y; mg1 = g; }
            if (c.z < mv2) { mv2 = c.z; mg2 = g; }
            if (c.w < mv3) { mv3 = c.w; mg3 = g; }
        }
    }
    s_mask[gh][lane] = mask;
    s_mv0[gh][lane] = mv0; s_mv1[gh][lane] = mv1;
    s_mv2[gh][lane] = mv2; s_mv3[gh][lane] = mv3;
    s_mg[gh][lane] = (unsigned)mg0 | ((unsigned)mg1 << 8)
                   | ((unsigned)mg2 << 16) | ((unsigned)mg3 << 24);
    __syncthreads();

    int c0 = 0, c1 = 0, c2 = 0, c3 = 0;
#pragma unroll
    for (int h = 0; h < 8; ++h) {
        const unsigned long long m = s_mask[h][lane];
        c0 += __popcll(m & 0xFFFFull);
        c1 += __popcll((m >> 16) & 0xFFFFull);
        c2 += __popcll((m >> 32) & 0xFFFFull);
        c3 += __popcll((m >> 48) & 0xFFFFull);
    }
    float b0 = s_mv0[0][lane], b1 = s_mv1[0][lane];
    float b2 = s_mv2[0][lane], b3 = s_mv3[0][lane];
    unsigned pk = s_mg[0][lane];
    int g0b = pk & 0xFF, g1b = (pk >> 8) & 0xFF;
    int g2b = (pk >> 16) & 0xFF, g3b = (pk >> 24) & 0xFF;
#pragma unroll
    for (int h = 1; h < 8; ++h) {                     // ascending h: first argmin
        const unsigned pkh = s_mg[h][lane];
        const float v0 = s_mv0[h][lane];
        if (v0 < b0) { b0 = v0; g0b = pkh & 0xFF; }
        const float v1 = s_mv1[h][lane];
        if (v1 < b1) { b1 = v1; g1b = (pkh >> 8) & 0xFF; }
        const float v2 = s_mv2[h][lane];
        if (v2 < b2) { b2 = v2; g2b = (pkh >> 16) & 0xFF; }
        const float v3 = s_mv3[h][lane];
        if (v3 < b3) { b3 = v3; g3b = (pkh >> 24) & 0xFF; }
    }
    const bool f0 = (c0 > 1), f1 = (c1 > 1), f2 = (c2 > 1), f3 = (c3 > 1);

    if (act) {
        float* mrow = out + (size_t)(b * 2 + 1) * Gn * Qn + q0;
#pragma unroll
        for (int j = 0; j < 16; ++j) {
            const int g = gbase + j;
            float4 o;
            o.x = (f0 ? (g == g0b) : ((mask >> j) & 1ull))        ? 1.0f : 0.0f;
            o.y = (f1 ? (g == g1b) : ((mask >> (16 + j)) & 1ull)) ? 1.0f : 0.0f;
            o.z = (f2 ? (g == g2b) : ((mask >> (32 + j)) & 1ull)) ? 1.0f : 0.0f;
            o.w = (f3 ? (g == g3b) : ((mask >> (48 + j)) & 1ull)) ? 1.0f : 0.0f;
            *reinterpret_cast<float4*>(mrow + (size_t)g * Qn) = o;
        }
    }
}

// ---------------------------------------------------------------------------
extern "C" void kernel_launch(void* const* d_in, const int* in_sizes, int n_in,
                              void* d_out, int out_size, void* d_ws, size_t ws_size,
                              hipStream_t stream) {
    (void)in_sizes; (void)n_in; (void)out_size;
    const float* logits = (const float*)d_in[0];
    const float* boxes  = (const float*)d_in[1];
    const int*   labels = (const int*)d_in[2];
    const float* tboxes = (const float*)d_in[3];
    float* out = (float*)d_out;

    float* thrv = (float*)((char*)d_ws + kThrvOff);   // [BS*Gn]
    int*   thri = (int*)  ((char*)d_ws + kThriOff);   // [BS*Gn]
    float* F    = (float*)((char*)d_ws + kFOff);      // [BS][Cn][Qn]

    const bool use_f = (ws_size >= kFOff + kFBytes);

    dim3 gF(BS * Gn);                     // one row per block, 8 waves
    if (use_f) {
        dim3 gP(Qn / 32, BS);             // 125 x 16
        kP_focal<<<gP, 256, 0, stream>>>(logits, F);
        kF<true><<<gF, 512, 0, stream>>>(boxes, labels, tboxes, logits, F,
                                         out, thrv, thri);
    } else {
        kF<false><<<gF, 512, 0, stream>>>(boxes, labels, tboxes, logits, nullptr,
                                          out, thrv, thri);
    }

    dim3 gC((Qn / 4 + 63) / 64, BS);      // 16 x 16, float4 columns
    kC5<<<gC, 512, 0, stream>>>(out, thrv, thri, out);
}